// Round 4
// baseline (554.684 us; speedup 1.0000x reference)
//
#include <hip/hip_runtime.h>
#include <hip/hip_bf16.h>
#include <hip/hip_fp16.h>
#include <stdint.h>

// ---------------------------------------------------------------------------
// CCRGNN r4: wave-per-graph GNN (2 graphs per 128-thread block, no block
// barriers in the graph path). GNN intermediates in fp16 (rel err 2^-11;
// r3's bf16 intermediates caused the 1.46e-2 absmax fail). Feature row bf16
// (GEMM input). GEMM operands in MFMA-fragment-tiled layout (r2-proven).
// Split-K GEMM2 + reduce fused into final gemm3.
// ---------------------------------------------------------------------------

typedef float f32x4 __attribute__((ext_vector_type(4)));
typedef short bf16x8 __attribute__((ext_vector_type(8)));

// ======================= wave-per-graph GNN ================================

__device__ __forceinline__ void seg_softmax(
    float* al, const unsigned short* sl, const int* off, float* sa, float d, int L)
{
  // lanes 0..38 = dst nodes. al[] holds e -> w; sa[] holds s -> 1/den.
  // Wave-lockstep: divergent trip counts still converge before the sa store.
  if (L < 39) {
    int p0 = off[L], p1 = off[L + 1];
    float mx = -1e30f;
    for (int p = p0; p < p1; ++p) {
      float e = sa[sl[p]] + d;
      e = (e > 0.f) ? e : 0.2f * e;          // leaky_relu(0.2)
      al[p] = e; mx = fmaxf(mx, e);
    }
    float den = 0.f;
    for (int p = p0; p < p1; ++p) { float wv = __expf(al[p] - mx); al[p] = wv; den += wv; }
    sa[L] = 1.f / (den + 1e-16f);
  }
}

__global__ __launch_bounds__(128) void gnn_wave(
    const float* __restrict__ x,
    const int* __restrict__ esrc, const int* __restrict__ edst,
    const float* __restrict__ W1, const float* __restrict__ a1s, const float* __restrict__ a1d, const float* __restrict__ b1,
    const float* __restrict__ W2, const float* __restrict__ a2s, const float* __restrict__ a2d, const float* __restrict__ b2,
    const float* __restrict__ W3, const float* __restrict__ a3s, const float* __restrict__ a3d, const float* __restrict__ b3,
    short* __restrict__ fA)                  // tiled [4096,3328] KT=52
{
  __shared__ __align__(16) __hip_bfloat16 featA[2][3328];
  __shared__ __align__(16) __half h2pA[2][2576];      // h2 fp16, stride 66
  __shared__ __align__(16) char HtRawA[2][5152];      // Ht1 f32[39*9] / Ht2 f16[39*66] / Ht3 f32[39*10]
  __shared__ __align__(16) __half h1hA[2][320];       // h1 fp16, stride 8
  __shared__ float alphaA[2][352];
  __shared__ unsigned short slsA[2][352];
  __shared__ int offA[2][40];
  __shared__ int curA[2][40];
  __shared__ float sarrA[2][40];
  __shared__ float sW3s[576];                         // W3 [64,9], block-shared

  const int tid = threadIdx.x, w = tid >> 6, L = tid & 63;
  const int g = blockIdx.x * 2 + w;

  for (int i = tid; i < 576; i += 128) sW3s[i] = W3[i];
  __syncthreads();                                    // only block barrier

  __hip_bfloat16* ft = featA[w];
  __half* hp = h2pA[w];
  float* Hf = (float*)HtRawA[w];
  __half* Hh = (__half*)HtRawA[w];
  __half* h1h = h1hA[w];
  float* al = alphaA[w];
  unsigned short* sl = slsA[w];
  int* off = offA[w]; int* cur = curA[w];
  float* sa = sarrA[w];

  // ---- x load + out0 (segment max over x) ----
  float xv = 0.f;
  if (L < 39) { xv = x[g * 39 + L]; ft[L] = __float2bfloat16(xv); }
  {
    float m = (L < 39) ? xv : -1e30f;
    for (int o = 32; o >= 1; o >>= 1) m = fmaxf(m, __shfl_xor(m, o, 64));
    if (L == 0) ft[3198] = __float2bfloat16(m);
  }

  // ---- CSR by dst (cur doubles as cnt) ----
  if (L < 39) cur[L] = 0;
  int els[6], eld[6];
  const int eb = g * 312, nb0 = g * 39;
#pragma unroll
  for (int it = 0; it < 6; ++it) {
    int e = it * 64 + L;
    int ls = 0, ld = 0;
    bool v = e < 351;
    if (v) {
      if (e < 312) { ls = esrc[eb + e] - nb0; ld = edst[eb + e] - nb0; }
      else         { ls = e - 312; ld = ls; }
      atomicAdd(&cur[ld], 1);
    }
    els[it] = v ? ls : -1; eld[it] = ld;
  }
  int c = (L < 39) ? cur[L] : 0;
  int incl = c;
  for (int o = 1; o < 64; o <<= 1) { int t = __shfl_up(incl, o, 64); if (L >= o) incl += t; }
  if (L < 39) { off[L] = incl - c; cur[L] = incl - c; }
  if (L == 38) off[39] = incl;                 // = 351
#pragma unroll
  for (int it = 0; it < 6; ++it)
    if (els[it] >= 0) { int p = atomicAdd(&cur[eld[it]], 1); sl[p] = (unsigned short)els[it]; }

  // ======== layer 1: Fin=1, Fout=8 (Ht1 = Hf fp32 stride 9) ========
  {
    const int fi = L & 7, ni = L >> 3;
    float w1v = W1[fi], b1v = b1[fi];
#pragma unroll
    for (int it = 0; it < 5; ++it) {
      int i = it * 8 + ni;
      if (i < 39) Hf[i * 9 + fi] = __shfl(xv, i, 64) * w1v;
    }
    {
      int row = (L < 39) ? L : 0;
      float s = 0.f, d = 0.f;
#pragma unroll
      for (int f = 0; f < 8; ++f) { float h = Hf[row * 9 + f]; s += h * a1s[f]; d += h * a1d[f]; }
      if (L < 39) sa[L] = s;
      seg_softmax(al, sl, off, sa, d, L);
    }
    float m1 = -1e30f;
#pragma unroll
    for (int it = 0; it < 5; ++it) {
      int i = it * 8 + ni;
      if (i < 39) {
        float acc = 0.f;
        int p1 = off[i + 1];
        for (int p = off[i]; p < p1; ++p) acc += al[p] * Hf[sl[p] * 9 + fi];
        float v = fmaxf(acc * sa[i] + b1v, 0.f);
        ft[39 + i * 8 + fi] = __float2bfloat16(v);
        h1h[i * 8 + fi] = __float2half(v);
        m1 = fmaxf(m1, v);
      }
    }
    m1 = fmaxf(m1, __shfl_xor(m1, 8, 64));
    m1 = fmaxf(m1, __shfl_xor(m1, 16, 64));
    m1 = fmaxf(m1, __shfl_xor(m1, 32, 64));
    if (L < 8) ft[3199 + L] = __float2bfloat16(m1);
  }

  // ======== layer 2: Fin=8, Fout=64 (lane = feature; Ht2 = Hh fp16 stride 66) ========
  {
    float w2k[8];
#pragma unroll
    for (int k = 0; k < 8; ++k) w2k[k] = W2[k * 64 + L];
    float a2sv = a2s[L], a2dv = a2d[L], b2v = b2[L];
    for (int i = 0; i < 39; ++i) {
      float hv = 0.f;
#pragma unroll
      for (int k = 0; k < 8; ++k) hv += __half2float(h1h[i * 8 + k]) * w2k[k];
      Hh[i * 66 + L] = __float2half(hv);
    }
    {
      int row = (L < 39) ? L : 0;
      float s = 0.f, d = 0.f;
      for (int f = 0; f < 64; ++f) {
        float h = __half2float(Hh[row * 66 + f]);
        s += h * __shfl(a2sv, f, 64); d += h * __shfl(a2dv, f, 64);
      }
      if (L < 39) sa[L] = s;
      seg_softmax(al, sl, off, sa, d, L);
    }
    float m2 = -1e30f;
    for (int i = 0; i < 39; ++i) {
      float acc = 0.f;
      int p0 = off[i], p1 = off[i + 1];
      for (int p = p0; p < p1; ++p) acc += al[p] * __half2float(Hh[sl[p] * 66 + L]);
      float v = fmaxf(acc * sa[i] + b2v, 0.f);
      ft[351 + i * 64 + L] = __float2bfloat16(v);
      hp[i * 66 + L] = __float2half(v);
      m2 = fmaxf(m2, v);
    }
    ft[3207 + L] = __float2bfloat16(m2);
  }

  // ======== layer 3: Fin=64, Fout=9 (Ht3 = Hf fp32 stride 10; Ht2 dead) ========
  {
    const int i7 = L / 9, f3 = L - 9 * i7;
    const bool act = L < 63;
    float b3v = act ? b3[f3] : 0.f;
#pragma unroll
    for (int it = 0; it < 6; ++it) {
      int i = it * 7 + i7;
      if (act && i < 39) {
        float acc = 0.f;
        for (int k = 0; k < 64; ++k) acc += __half2float(hp[i * 66 + k]) * sW3s[k * 9 + f3];
        Hf[i * 10 + f3] = acc;
      }
    }
    {
      int row = (L < 39) ? L : 0;
      float s = 0.f, d = 0.f;
#pragma unroll
      for (int f = 0; f < 9; ++f) { float h = Hf[row * 10 + f]; s += h * a3s[f]; d += h * a3d[f]; }
      if (L < 39) sa[L] = s;
      seg_softmax(al, sl, off, sa, d, L);
    }
#pragma unroll
    for (int it = 0; it < 6; ++it) {
      int i = it * 7 + i7;
      if (act && i < 39) {
        float acc = 0.f;
        int p1 = off[i + 1];
        for (int p = off[i]; p < p1; ++p) acc += al[p] * Hf[sl[p] * 10 + f3];
        float v = fmaxf(acc * sa[i] + b3v, 0.f);
        ft[2847 + i * 9 + f3] = __float2bfloat16(v);
      }
    }
    if (L < 9) {
      float m = -1e30f;
      for (int i = 0; i < 39; ++i) m = fmaxf(m, __bfloat162float(ft[2847 + i * 9 + L]));
      ft[3271 + L] = __float2bfloat16(m);
    }
    if (L < 48) ft[3280 + L] = __float2bfloat16(0.f);
  }

  // ---- tiled writeout: 416 chunks of 16B, lane-contiguous LDS reads ----
  {
    const int rt = g >> 7, mi = (g >> 4) & 7, lrow = g & 15;
    const size_t rowbase = (size_t)rt * 52 * 8192;
#pragma unroll
    for (int it = 0; it < 7; ++it) {
      int c8 = it * 64 + L;
      if (c8 < 416) {
        int cc = c8 * 8;
        int kt = cc >> 6, kq = (cc >> 5) & 1, lch = (cc >> 3) & 3;
        bf16x8 v = *(const bf16x8*)&ft[cc];
        size_t addr = rowbase + (size_t)kt * 8192 + (size_t)(mi * 2 + kq) * 512
                    + (size_t)(lrow + 16 * lch) * 8;
        *(bf16x8*)&fA[addr] = v;
      }
    }
  }
}

// ===== fp32 [K0,N0] -> bf16 fragment-tiled [Np,Kp], 64x64 tiles, float4 =====

__global__ __launch_bounds__(256) void conv_tiled(
    const float* __restrict__ W, short* __restrict__ WT,
    int K0, int N0, int KT)     // grid: (Kp/64, Np/64)
{
  __shared__ float t[64][68];
  const int kb = blockIdx.x * 64, nb = blockIdx.y * 64;
  const int tid = threadIdx.x;
  const int tx = tid & 15, ty = tid >> 4;
#pragma unroll
  for (int r = 0; r < 4; ++r) {
    int k = kb + ty + r * 16, n = nb + tx * 4;
    float4 v = make_float4(0.f, 0.f, 0.f, 0.f);
    if (k < K0 && n < N0) v = *(const float4*)&W[(size_t)k * N0 + n];   // N0 % 4 == 0
    t[ty + r * 16][tx * 4 + 0] = v.x; t[ty + r * 16][tx * 4 + 1] = v.y;
    t[ty + r * 16][tx * 4 + 2] = v.z; t[ty + r * 16][tx * 4 + 3] = v.w;
  }
  __syncthreads();
  const int nl = tid >> 2, kc0 = tid & 3;
#pragma unroll
  for (int h = 0; h < 2; ++h) {
    int kc = kc0 + h * 4;
    int n = nb + nl, k = kb + kc * 8;
    union { bf16x8 v; __hip_bfloat16 b[8]; } z;
#pragma unroll
    for (int j = 0; j < 8; ++j) z.b[j] = __float2bfloat16(t[kc * 8 + j][nl]);
    int rt = n >> 7, mi = (n >> 4) & 7, lr = n & 15;
    int kt = k >> 6, kq = (k >> 5) & 1, lc = (k >> 3) & 3;
    size_t addr = ((((size_t)rt * KT) + kt) * 16 + mi * 2 + kq) * 512 + ((size_t)lr + 16 * lc) * 8;
    *(bf16x8*)&WT[addr] = z.v;
  }
}

// ======================= tiled bf16 MFMA GEMM ==============================

__device__ __forceinline__ void gld_lds16(const void* gptr, void* l) {
  typedef const __attribute__((address_space(1))) unsigned int GU;
  typedef __attribute__((address_space(3))) unsigned int LU;
  __builtin_amdgcn_global_load_lds((GU*)gptr, (LU*)l, 16, 0, 0);
}

// MODE 0: C tiled bf16 (next GEMM's A, outKT = Nn/64), +bias +relu
// MODE 1: fp32 partials P[splits][4096][Nn] row-major
template<int MODE>
__global__ __launch_bounds__(256) void gemm_tiled(
    const short* __restrict__ A, const short* __restrict__ B,
    const float* __restrict__ bias, int Nreal,
    void* __restrict__ Cout, int Nn, int KT, int ktPerSplit, int outKT)
{
  __shared__ __align__(16) short lA[8192];
  __shared__ __align__(16) short lB[8192];
  const int tid = threadIdx.x;
  const int w = tid >> 6, L = tid & 63;
  const int lrow = L & 15, lch = L >> 4;
  const int mt = blockIdx.y, nt = blockIdx.x;
  const int mw = (w >> 1) * 4, nw = (w & 1) * 4;
  const int kt0 = blockIdx.z * ktPerSplit, kt1 = kt0 + ktPerSplit;

  const short* Ab = A + ((size_t)mt * KT) * 8192 + (size_t)L * 8;
  const short* Bb = B + ((size_t)nt * KT) * 8192 + (size_t)L * 8;

  f32x4 acc[4][4] = {};

  for (int kt = kt0; kt < kt1; ++kt) {
    const short* Ak = Ab + (size_t)kt * 8192;
    const short* Bk = Bb + (size_t)kt * 8192;
#pragma unroll
    for (int j = 0; j < 4; ++j) {
      int st = w * 4 + j;
      gld_lds16(Ak + st * 512, &lA[st * 512]);
      gld_lds16(Bk + st * 512, &lB[st * 512]);
    }
    __syncthreads();
#pragma unroll
    for (int kk = 0; kk < 2; ++kk) {
      bf16x8 af[4], bfr[4];
#pragma unroll
      for (int i = 0; i < 4; ++i) {
        af[i]  = *(const bf16x8*)&lA[((mw + i) * 2 + kk) * 512 + L * 8];
        bfr[i] = *(const bf16x8*)&lB[((nw + i) * 2 + kk) * 512 + L * 8];
      }
#pragma unroll
      for (int i = 0; i < 4; ++i)
#pragma unroll
        for (int j = 0; j < 4; ++j)
          acc[i][j] = __builtin_amdgcn_mfma_f32_16x16x32_bf16(af[i], bfr[j], acc[i][j], 0, 0, 0);
    }
    __syncthreads();
  }

  if (MODE == 0) {
    __hip_bfloat16* C = (__hip_bfloat16*)Cout;
#pragma unroll
    for (int j = 0; j < 4; ++j) {
      int n = nt * 128 + (nw + j) * 16 + lrow;
      float bn = (n < Nreal) ? bias[n] : 0.f;
      int kt = n >> 6, kq = (n >> 5) & 1, lc2 = (n >> 3) & 3, j2 = n & 7;
#pragma unroll
      for (int i = 0; i < 4; ++i) {
        int mi = mw + i;
        size_t base = ((((size_t)mt * outKT + kt) * 16) + mi * 2 + kq) * 512
                      + (size_t)(lch * 4) * 8 + (size_t)lc2 * 128 + j2;
#pragma unroll
        for (int r = 0; r < 4; ++r)
          C[base + r * 8] = __float2bfloat16(fmaxf(acc[i][j][r] + bn, 0.f));
      }
    }
  } else {
    float* P = (float*)Cout + (size_t)blockIdx.z * 4096 * 1024;
#pragma unroll
    for (int j = 0; j < 4; ++j) {
      int n = nt * 128 + (nw + j) * 16 + lrow;
#pragma unroll
      for (int i = 0; i < 4; ++i)
#pragma unroll
        for (int r = 0; r < 4; ++r) {
          int m = mt * 128 + (mw + i) * 16 + lch * 4 + r;
          P[(size_t)m * Nn + n] = acc[i][j][r];
        }
    }
  }
}

// ====== final: relu(P0+P1+b2) @ W3 + b3 -> fp32 out (split-K reduce fused) ==

__global__ __launch_bounds__(256) void gemm3_fused(
    const float* __restrict__ P,      // [2][4096][1024]
    const float* __restrict__ b2v,    // lb2 [1024]
    const float* __restrict__ W3,     // lW3 [1024,9]
    const float* __restrict__ b3v,    // lb3 [9]
    float* __restrict__ out)          // [4096,9]
{
  __shared__ float sW3[9 * 1024];
  int tid = threadIdx.x;
  for (int i = tid; i < 9216; i += 256) { int k = i / 9, j = i - 9 * k; sW3[j * 1024 + k] = W3[i]; }
  __syncthreads();
  int row = blockIdx.x * 4 + (tid >> 6);
  int lane = tid & 63;
  const float* p0 = P + (size_t)row * 1024;
  const float* p1 = p0 + (size_t)4096 * 1024;
  float acc[9] = {0, 0, 0, 0, 0, 0, 0, 0, 0};
  for (int t = 0; t < 16; ++t) {
    int k = lane + 64 * t;
    float c = fmaxf(p0[k] + p1[k] + b2v[k], 0.f);
#pragma unroll
    for (int j = 0; j < 9; ++j) acc[j] += c * sW3[j * 1024 + k];
  }
#pragma unroll
  for (int j = 0; j < 9; ++j) {
    float v = acc[j];
    v += __shfl_down(v, 32, 64);
    v += __shfl_down(v, 16, 64);
    v += __shfl_down(v, 8, 64);
    v += __shfl_down(v, 4, 64);
    v += __shfl_down(v, 2, 64);
    v += __shfl_down(v, 1, 64);
    if (lane == 0) out[(size_t)row * 9 + j] = v + b3v[j];
  }
}

// ============================= launch =======================================

extern "C" void kernel_launch(void* const* d_in, const int* in_sizes, int n_in,
                              void* d_out, int out_size, void* d_ws, size_t ws_size,
                              hipStream_t stream)
{
  const float* x   = (const float*)d_in[0];
  const int*   ei  = (const int*)d_in[1];
  const float* W1  = (const float*)d_in[3];
  const float* a1s = (const float*)d_in[4];
  const float* a1d = (const float*)d_in[5];
  const float* b1  = (const float*)d_in[6];
  const float* W2  = (const float*)d_in[7];
  const float* a2s = (const float*)d_in[8];
  const float* a2d = (const float*)d_in[9];
  const float* b2  = (const float*)d_in[10];
  const float* W3  = (const float*)d_in[11];
  const float* a3s = (const float*)d_in[12];
  const float* a3d = (const float*)d_in[13];
  const float* b3  = (const float*)d_in[14];
  const float* lW1 = (const float*)d_in[15];
  const float* lb1 = (const float*)d_in[16];
  const float* lW2 = (const float*)d_in[17];
  const float* lb2 = (const float*)d_in[18];
  const float* lW3 = (const float*)d_in[19];
  const float* lb3 = (const float*)d_in[20];

  const int E = 4096 * 39 * 8;
  const int* esrc = ei;
  const int* edst = ei + E;

  // ws (bf16 elems): fA 13.6M | W1T 17.0M | C1 21.0M | W2T 5.2M  (~114 MB)
  short* fA  = (short*)d_ws;                       // tiled [4096,3328] KT=52
  short* W1T = fA  + (size_t)4096 * 3328;          // tiled [5120,3328] KT=52
  short* C1  = W1T + (size_t)5120 * 3328;          // tiled [4096,5120] KT=80
  short* W2T = C1  + (size_t)4096 * 5120;          // tiled [1024,5120] KT=80
  float* P   = (float*)d_ws;                       // 2x[4096,1024] fp32, aliases fA+W1T (dead)

  conv_tiled<<<dim3(3328 / 64, 5120 / 64), 256, 0, stream>>>(lW1, W1T, 3280, 5000, 52);
  conv_tiled<<<dim3(5120 / 64, 1024 / 64), 256, 0, stream>>>(lW2, W2T, 5000, 1024, 80);
  gnn_wave<<<2048, 128, 0, stream>>>(x, esrc, edst,
                                     W1, a1s, a1d, b1, W2, a2s, a2d, b2, W3, a3s, a3d, b3, fA);
  gemm_tiled<0><<<dim3(40, 32, 1), 256, 0, stream>>>(fA, W1T, lb1, 5000, C1, 5120, 52, 52, 80);
  gemm_tiled<1><<<dim3(8, 32, 2), 256, 0, stream>>>(C1, W2T, nullptr, 1024, P, 1024, 80, 40, 0);
  gemm3_fused<<<1024, 256, 0, stream>>>(P, lb2, lW3, lb3, (float*)d_out);
}

// Round 5
// 487.867 us; speedup vs baseline: 1.1370x; 1.1370x over previous
//
#include <hip/hip_runtime.h>
#include <hip/hip_bf16.h>
#include <hip/hip_fp16.h>
#include <stdint.h>

// ---------------------------------------------------------------------------
// CCRGNN r5: GNN = one 128-thread block (2 waves) per graph. No featA staging:
// every feature element is stored DIRECTLY to the fragment-tiled global fA via
// colAddr(g,c) as it is computed (consecutive lanes -> consecutive c -> 16B
// segments). fp16 intermediates (r4-proven numerics). LDS ~18.6KB/block ->
// 8 blocks/CU (~50% occ) vs r4's 43KB (14.8% occ, latency-bound at 194us).
// GEMMs unchanged (fragment-tiled operands, r2-proven).
// ---------------------------------------------------------------------------

typedef float f32x4 __attribute__((ext_vector_type(4)));
typedef short bf16x8 __attribute__((ext_vector_type(8)));

// ======================= block-per-graph GNN (2 waves) =====================

__device__ __forceinline__ void seg_softmax(
    float* al, const unsigned short* sl, const int* off, float* sa,
    const float* dbuf, int L)
{
  // wave0 lanes; L<39 = dst node. al: e -> unnormalized w. sa: s -> 1/den.
  if (L < 39) {
    int p0 = off[L], p1 = off[L + 1];
    float d = dbuf[L];
    float mx = -1e30f;
    for (int p = p0; p < p1; ++p) {
      float e = sa[sl[p]] + d;
      e = (e > 0.f) ? e : 0.2f * e;          // leaky_relu(0.2)
      al[p] = e; mx = fmaxf(mx, e);
    }
    float den = 0.f;
    for (int p = p0; p < p1; ++p) { float wv = __expf(al[p] - mx); al[p] = wv; den += wv; }
    sa[L] = 1.f / (den + 1e-16f);            // wave-lockstep: pass1 reads done
  }
}

__global__ __launch_bounds__(128) void gnn_block(
    const float* __restrict__ x,
    const int* __restrict__ esrc, const int* __restrict__ edst,
    const float* __restrict__ W1, const float* __restrict__ a1s, const float* __restrict__ a1d, const float* __restrict__ b1,
    const float* __restrict__ W2, const float* __restrict__ a2s, const float* __restrict__ a2d, const float* __restrict__ b2,
    const float* __restrict__ W3, const float* __restrict__ a3s, const float* __restrict__ a3d, const float* __restrict__ b3,
    __hip_bfloat16* __restrict__ fA)         // tiled [4096,3328] KT=52
{
  __shared__ __align__(16) char HtU[5152];   // Ht1 f32 s9 | Ht2 f16 s66 | Ht3 f32 s10
  __shared__ __align__(16) __half h2buf[2576];  // h2 fp16, stride 66
  __shared__ float h3b[352];                 // h3 fp32, stride 9
  __shared__ __half h1h[320];                // h1 fp16, stride 8
  __shared__ float al[352];
  __shared__ unsigned short sl[352];
  __shared__ int off[40];
  __shared__ int cur[40];
  __shared__ float sa[40], dbuf[40], xbuf[40];
  __shared__ float a2buf[128];               // a2s | a2d
  __shared__ float mx[132];                  // out0 m1 m2 m3 pad
  __shared__ float sW3s[576];                // W3 [64][9]

  const int tid = threadIdx.x, g = blockIdx.x;
  float* Hf  = (float*)HtU;                  // Ht1 (stride 9), Ht3 (stride 10)
  __half* Hh = (__half*)HtU;                 // Ht2 (stride 66)

  // tiled column address for row g (in bf16 elements)
  const int rt = g >> 7, mi = (g >> 4) & 7, lrow = g & 15;
  const size_t gbase = (size_t)rt * 52 * 8192 + (size_t)(mi * 2) * 512 + (size_t)lrow * 8;
#define COLADDR(c) (gbase + (size_t)((c) >> 6) * 8192 + (size_t)(((c) >> 5) & 1) * 512 \
                    + (size_t)(((c) >> 3) & 3) * 128 + ((c) & 7))

  // preload small params + x
  for (int i = tid; i < 576; i += 128) sW3s[i] = W3[i];
  a2buf[tid] = (tid < 64) ? a2s[tid] : a2d[tid - 64];
  float xv = 0.f;
  if (tid < 40) cur[tid] = 0;
  if (tid < 39) { xv = x[g * 39 + tid]; xbuf[tid] = xv; }

  // out0 = max over x (wave0)
  if (tid < 64) {
    float m = (tid < 39) ? xv : -1e30f;
    for (int o = 32; o >= 1; o >>= 1) m = fmaxf(m, __shfl_xor(m, o, 64));
    if (tid == 0) mx[0] = m;
  }
  // res(x) cols 0..38
  if (tid < 39) fA[COLADDR(tid)] = __float2bfloat16(xv);
  __syncthreads();

  // ---- CSR by dst ----
  int els[3], eld[3];
  const int eb = g * 312, nb0 = g * 39;
#pragma unroll
  for (int it = 0; it < 3; ++it) {
    int e = it * 128 + tid, ls = -1, ld = 0;
    if (e < 351) {
      if (e < 312) { ls = esrc[eb + e] - nb0; ld = edst[eb + e] - nb0; }
      else         { ls = e - 312; ld = ls; }
      atomicAdd(&cur[ld], 1);
    }
    els[it] = ls; eld[it] = ld;
  }
  __syncthreads();
  if (tid < 64) {                              // wave0 prefix scan
    int c = (tid < 39) ? cur[tid] : 0;
    int incl = c;
    for (int o = 1; o < 64; o <<= 1) { int t = __shfl_up(incl, o, 64); if (tid >= o) incl += t; }
    if (tid < 39) off[tid] = incl - c;
    if (tid == 38) off[39] = incl;             // 351
  }
  __syncthreads();
  if (tid < 39) cur[tid] = off[tid];
  __syncthreads();
#pragma unroll
  for (int it = 0; it < 3; ++it)
    if (els[it] >= 0) { int p = atomicAdd(&cur[eld[it]], 1); sl[p] = (unsigned short)els[it]; }
  __syncthreads();

  // ======== layer 1: Fin=1 Fout=8 (Ht1 = Hf stride 9) ========
  {
    const float w1r = W1[tid & 7];
#pragma unroll
    for (int it = 0; it < 3; ++it) {
      int slot = it * 128 + tid;
      if (slot < 312) { int i = slot >> 3, fi = slot & 7; Hf[i * 9 + fi] = xbuf[i] * w1r; }
    }
  }
  __syncthreads();
  {
    int node = tid & 63;
    if (node < 39) {
      const float* av = (tid < 64) ? a1s : a1d;
      float s = 0.f;
#pragma unroll
      for (int f = 0; f < 8; ++f) s += Hf[node * 9 + f] * av[f];
      if (tid < 64) sa[node] = s; else dbuf[node] = s;
    }
  }
  __syncthreads();
  if (tid < 64) seg_softmax(al, sl, off, sa, dbuf, tid);
  __syncthreads();
  {
    const float b1r = b1[tid & 7];
#pragma unroll
    for (int it = 0; it < 3; ++it) {
      int slot = it * 128 + tid;
      if (slot < 312) {
        int i = slot >> 3, fi = slot & 7;
        float acc = 0.f;
        int p1 = off[i + 1];
        for (int p = off[i]; p < p1; ++p) acc += al[p] * Hf[sl[p] * 9 + fi];
        float v = fmaxf(acc * sa[i] + b1r, 0.f);
        h1h[i * 8 + fi] = __float2half(v);
        int c = 39 + slot;
        fA[COLADDR(c)] = __float2bfloat16(v);
      }
    }
  }
  __syncthreads();

  // ======== layer 2: Fin=8 Fout=64 (Ht2 = Hh stride 66) ========
  {
    const int f = tid & 63;
    float w2k[8];
#pragma unroll
    for (int k = 0; k < 8; ++k) w2k[k] = W2[k * 64 + f];
    for (int it = 0; it < 20; ++it) {
      int i = it * 2 + (tid >> 6);
      if (i < 39) {
        float hv = 0.f;
#pragma unroll
        for (int k = 0; k < 8; ++k) hv += __half2float(h1h[i * 8 + k]) * w2k[k];
        Hh[i * 66 + f] = __float2half(hv);
      }
    }
  }
  __syncthreads();
  {
    int node = tid & 63;
    if (node < 39) {
      const float* ab = a2buf + (tid & 64);       // wave0: a2s, wave1: a2d
      float s = 0.f;
      for (int f = 0; f < 64; ++f) s += __half2float(Hh[node * 66 + f]) * ab[f];
      if (tid < 64) sa[node] = s; else dbuf[node] = s;
    }
  }
  __syncthreads();
  if (tid < 64) seg_softmax(al, sl, off, sa, dbuf, tid);
  __syncthreads();
  {
    const int f = tid & 63;
    const float b2r = b2[f];
    for (int it = 0; it < 20; ++it) {
      int i = it * 2 + (tid >> 6);
      if (i < 39) {
        float acc = 0.f;
        int p1 = off[i + 1];
        for (int p = off[i]; p < p1; ++p) acc += al[p] * __half2float(Hh[sl[p] * 66 + f]);
        float v = fmaxf(acc * sa[i] + b2r, 0.f);
        h2buf[i * 66 + f] = __float2half(v);
        int c = 351 + i * 64 + f;
        fA[COLADDR(c)] = __float2bfloat16(v);
      }
    }
  }
  __syncthreads();

  // ======== layer 3: Fin=64 Fout=9 (Ht3 = Hf stride 10; Ht2 dead) ========
  {
#pragma unroll
    for (int it = 0; it < 3; ++it) {
      int slot = it * 128 + tid;
      if (slot < 351) {
        int i = slot / 9, f3 = slot - 9 * i;
        float acc = 0.f;
        for (int k = 0; k < 64; ++k) acc += __half2float(h2buf[i * 66 + k]) * sW3s[k * 9 + f3];
        Hf[i * 10 + f3] = acc;
      }
    }
  }
  __syncthreads();
  {
    int node = tid & 63;
    if (node < 39) {
      const float* av = (tid < 64) ? a3s : a3d;
      float s = 0.f;
#pragma unroll
      for (int f3 = 0; f3 < 9; ++f3) s += Hf[node * 10 + f3] * av[f3];
      if (tid < 64) sa[node] = s; else dbuf[node] = s;
    }
  }
  __syncthreads();
  if (tid < 64) seg_softmax(al, sl, off, sa, dbuf, tid);
  __syncthreads();
  {
#pragma unroll
    for (int it = 0; it < 3; ++it) {
      int slot = it * 128 + tid;
      if (slot < 351) {
        int i = slot / 9, f3 = slot - 9 * i;
        float acc = 0.f;
        int p1 = off[i + 1];
        for (int p = off[i]; p < p1; ++p) acc += al[p] * Hf[sl[p] * 10 + f3];
        float v = fmaxf(acc * sa[i] + b3[f3], 0.f);
        h3b[slot] = v;
        int c = 2847 + slot;
        fA[COLADDR(c)] = __float2bfloat16(v);
      }
    }
  }
  __syncthreads();

  // ---- segment maxes + pad (cols 3198..3327) ----
  if (tid >= 1 && tid < 9) {
    int f = tid - 1; float m = -1e30f;
    for (int i = 0; i < 39; ++i) m = fmaxf(m, __half2float(h1h[i * 8 + f]));
    mx[tid] = m;
  } else if (tid >= 9 && tid < 73) {
    int f = tid - 9; float m = -1e30f;
    for (int i = 0; i < 39; ++i) m = fmaxf(m, __half2float(h2buf[i * 66 + f]));
    mx[tid] = m;
  } else if (tid >= 73 && tid < 82) {
    int f = tid - 73; float m = -1e30f;
    for (int i = 0; i < 39; ++i) m = fmaxf(m, h3b[i * 9 + f]);
    mx[tid] = m;
  } else if (tid >= 82 && tid < 130) {
    mx[tid] = 0.f;
  }
  __syncthreads();
  if (tid < 130) {
    int c = 3198 + tid;
    fA[COLADDR(c)] = __float2bfloat16(mx[tid]);
  }
#undef COLADDR
}

// ===== fp32 [K0,N0] -> bf16 fragment-tiled [Np,Kp], 64x64 tiles, float4 =====

__global__ __launch_bounds__(256) void conv_tiled(
    const float* __restrict__ W, short* __restrict__ WT,
    int K0, int N0, int KT)     // grid: (Kp/64, Np/64)
{
  __shared__ float t[64][68];
  const int kb = blockIdx.x * 64, nb = blockIdx.y * 64;
  const int tid = threadIdx.x;
  const int tx = tid & 15, ty = tid >> 4;
#pragma unroll
  for (int r = 0; r < 4; ++r) {
    int k = kb + ty + r * 16, n = nb + tx * 4;
    float4 v = make_float4(0.f, 0.f, 0.f, 0.f);
    if (k < K0 && n < N0) v = *(const float4*)&W[(size_t)k * N0 + n];   // N0 % 4 == 0
    t[ty + r * 16][tx * 4 + 0] = v.x; t[ty + r * 16][tx * 4 + 1] = v.y;
    t[ty + r * 16][tx * 4 + 2] = v.z; t[ty + r * 16][tx * 4 + 3] = v.w;
  }
  __syncthreads();
  const int nl = tid >> 2, kc0 = tid & 3;
#pragma unroll
  for (int h = 0; h < 2; ++h) {
    int kc = kc0 + h * 4;
    int n = nb + nl, k = kb + kc * 8;
    union { bf16x8 v; __hip_bfloat16 b[8]; } z;
#pragma unroll
    for (int j = 0; j < 8; ++j) z.b[j] = __float2bfloat16(t[kc * 8 + j][nl]);
    int rt = n >> 7, mi = (n >> 4) & 7, lr = n & 15;
    int kt = k >> 6, kq = (k >> 5) & 1, lc = (k >> 3) & 3;
    size_t addr = ((((size_t)rt * KT) + kt) * 16 + mi * 2 + kq) * 512 + ((size_t)lr + 16 * lc) * 8;
    *(bf16x8*)&WT[addr] = z.v;
  }
}

// ======================= tiled bf16 MFMA GEMM ==============================

__device__ __forceinline__ void gld_lds16(const void* gptr, void* l) {
  typedef const __attribute__((address_space(1))) unsigned int GU;
  typedef __attribute__((address_space(3))) unsigned int LU;
  __builtin_amdgcn_global_load_lds((GU*)gptr, (LU*)l, 16, 0, 0);
}

// MODE 0: C tiled bf16 (next GEMM's A, outKT = Nn/64), +bias +relu
// MODE 1: fp32 partials P[splits][4096][Nn] row-major
template<int MODE>
__global__ __launch_bounds__(256) void gemm_tiled(
    const short* __restrict__ A, const short* __restrict__ B,
    const float* __restrict__ bias, int Nreal,
    void* __restrict__ Cout, int Nn, int KT, int ktPerSplit, int outKT)
{
  __shared__ __align__(16) short lA[8192];
  __shared__ __align__(16) short lB[8192];
  const int tid = threadIdx.x;
  const int w = tid >> 6, L = tid & 63;
  const int lrow = L & 15, lch = L >> 4;
  const int mt = blockIdx.y, nt = blockIdx.x;
  const int mw = (w >> 1) * 4, nw = (w & 1) * 4;
  const int kt0 = blockIdx.z * ktPerSplit, kt1 = kt0 + ktPerSplit;

  const short* Ab = A + ((size_t)mt * KT) * 8192 + (size_t)L * 8;
  const short* Bb = B + ((size_t)nt * KT) * 8192 + (size_t)L * 8;

  f32x4 acc[4][4] = {};

  for (int kt = kt0; kt < kt1; ++kt) {
    const short* Ak = Ab + (size_t)kt * 8192;
    const short* Bk = Bb + (size_t)kt * 8192;
#pragma unroll
    for (int j = 0; j < 4; ++j) {
      int st = w * 4 + j;
      gld_lds16(Ak + st * 512, &lA[st * 512]);
      gld_lds16(Bk + st * 512, &lB[st * 512]);
    }
    __syncthreads();
#pragma unroll
    for (int kk = 0; kk < 2; ++kk) {
      bf16x8 af[4], bfr[4];
#pragma unroll
      for (int i = 0; i < 4; ++i) {
        af[i]  = *(const bf16x8*)&lA[((mw + i) * 2 + kk) * 512 + L * 8];
        bfr[i] = *(const bf16x8*)&lB[((nw + i) * 2 + kk) * 512 + L * 8];
      }
#pragma unroll
      for (int i = 0; i < 4; ++i)
#pragma unroll
        for (int j = 0; j < 4; ++j)
          acc[i][j] = __builtin_amdgcn_mfma_f32_16x16x32_bf16(af[i], bfr[j], acc[i][j], 0, 0, 0);
    }
    __syncthreads();
  }

  if (MODE == 0) {
    __hip_bfloat16* C = (__hip_bfloat16*)Cout;
#pragma unroll
    for (int j = 0; j < 4; ++j) {
      int n = nt * 128 + (nw + j) * 16 + lrow;
      float bn = (n < Nreal) ? bias[n] : 0.f;
      int kt = n >> 6, kq = (n >> 5) & 1, lc2 = (n >> 3) & 3, j2 = n & 7;
#pragma unroll
      for (int i = 0; i < 4; ++i) {
        int mi = mw + i;
        size_t base = ((((size_t)mt * outKT + kt) * 16) + mi * 2 + kq) * 512
                      + (size_t)(lch * 4) * 8 + (size_t)lc2 * 128 + j2;
#pragma unroll
        for (int r = 0; r < 4; ++r)
          C[base + r * 8] = __float2bfloat16(fmaxf(acc[i][j][r] + bn, 0.f));
      }
    }
  } else {
    float* P = (float*)Cout + (size_t)blockIdx.z * 4096 * 1024;
#pragma unroll
    for (int j = 0; j < 4; ++j) {
      int n = nt * 128 + (nw + j) * 16 + lrow;
#pragma unroll
      for (int i = 0; i < 4; ++i)
#pragma unroll
        for (int r = 0; r < 4; ++r) {
          int m = mt * 128 + (mw + i) * 16 + lch * 4 + r;
          P[(size_t)m * Nn + n] = acc[i][j][r];
        }
    }
  }
}

// ====== final: relu(P0+P1+b2) @ W3 + b3 -> fp32 out (split-K reduce fused) ==

__global__ __launch_bounds__(256) void gemm3_fused(
    const float* __restrict__ P,      // [2][4096][1024]
    const float* __restrict__ b2v,    // lb2 [1024]
    const float* __restrict__ W3,     // lW3 [1024,9]
    const float* __restrict__ b3v,    // lb3 [9]
    float* __restrict__ out)          // [4096,9]
{
  __shared__ float sW3[9 * 1024];
  int tid = threadIdx.x;
  for (int i = tid; i < 9216; i += 256) { int k = i / 9, j = i - 9 * k; sW3[j * 1024 + k] = W3[i]; }
  __syncthreads();
  int row = blockIdx.x * 4 + (tid >> 6);
  int lane = tid & 63;
  const float* p0 = P + (size_t)row * 1024;
  const float* p1 = p0 + (size_t)4096 * 1024;
  float acc[9] = {0, 0, 0, 0, 0, 0, 0, 0, 0};
  for (int t = 0; t < 16; ++t) {
    int k = lane + 64 * t;
    float c = fmaxf(p0[k] + p1[k] + b2v[k], 0.f);
#pragma unroll
    for (int j = 0; j < 9; ++j) acc[j] += c * sW3[j * 1024 + k];
  }
#pragma unroll
  for (int j = 0; j < 9; ++j) {
    float v = acc[j];
    v += __shfl_down(v, 32, 64);
    v += __shfl_down(v, 16, 64);
    v += __shfl_down(v, 8, 64);
    v += __shfl_down(v, 4, 64);
    v += __shfl_down(v, 2, 64);
    v += __shfl_down(v, 1, 64);
    if (lane == 0) out[(size_t)row * 9 + j] = v + b3v[j];
  }
}

// ============================= launch =======================================

extern "C" void kernel_launch(void* const* d_in, const int* in_sizes, int n_in,
                              void* d_out, int out_size, void* d_ws, size_t ws_size,
                              hipStream_t stream)
{
  const float* x   = (const float*)d_in[0];
  const int*   ei  = (const int*)d_in[1];
  const float* W1  = (const float*)d_in[3];
  const float* a1s = (const float*)d_in[4];
  const float* a1d = (const float*)d_in[5];
  const float* b1  = (const float*)d_in[6];
  const float* W2  = (const float*)d_in[7];
  const float* a2s = (const float*)d_in[8];
  const float* a2d = (const float*)d_in[9];
  const float* b2  = (const float*)d_in[10];
  const float* W3  = (const float*)d_in[11];
  const float* a3s = (const float*)d_in[12];
  const float* a3d = (const float*)d_in[13];
  const float* b3  = (const float*)d_in[14];
  const float* lW1 = (const float*)d_in[15];
  const float* lb1 = (const float*)d_in[16];
  const float* lW2 = (const float*)d_in[17];
  const float* lb2 = (const float*)d_in[18];
  const float* lW3 = (const float*)d_in[19];
  const float* lb3 = (const float*)d_in[20];

  const int E = 4096 * 39 * 8;
  const int* esrc = ei;
  const int* edst = ei + E;

  // ws (bf16 elems): fA 13.6M | W1T 17.0M | C1 21.0M | W2T 5.2M  (~114 MB)
  short* fA  = (short*)d_ws;                       // tiled [4096,3328] KT=52
  short* W1T = fA  + (size_t)4096 * 3328;          // tiled [5120,3328] KT=52
  short* C1  = W1T + (size_t)5120 * 3328;          // tiled [4096,5120] KT=80
  short* W2T = C1  + (size_t)4096 * 5120;          // tiled [1024,5120] KT=80
  float* P   = (float*)d_ws;                       // 2x[4096,1024] fp32, aliases fA+W1T (dead)

  conv_tiled<<<dim3(3328 / 64, 5120 / 64), 256, 0, stream>>>(lW1, W1T, 3280, 5000, 52);
  conv_tiled<<<dim3(5120 / 64, 1024 / 64), 256, 0, stream>>>(lW2, W2T, 5000, 1024, 80);
  gnn_block<<<4096, 128, 0, stream>>>(x, esrc, edst,
                                      W1, a1s, a1d, b1, W2, a2s, a2d, b2, W3, a3s, a3d, b3,
                                      (__hip_bfloat16*)fA);
  gemm_tiled<0><<<dim3(40, 32, 1), 256, 0, stream>>>(fA, W1T, lb1, 5000, C1, 5120, 52, 52, 80);
  gemm_tiled<1><<<dim3(8, 32, 2), 256, 0, stream>>>(C1, W2T, nullptr, 1024, P, 1024, 80, 40, 0);
  gemm3_fused<<<1024, 256, 0, stream>>>(P, lb2, lW3, lb3, (float*)d_out);
}